// Round 4
// baseline (151.539 us; speedup 1.0000x reference)
//
#include <hip/hip_runtime.h>

// B=2,T=512,C=256,HID=1024. ROWS=1024.
// Reference collapses (attn branch *0.0) to:
//   xp = x + bp;  out = xp + bf2 + relu(LN(xp,g2,b2) @ W1.T + bf1) @ W2.T
// K1 prep_w: W1/W2 fp32 -> bf16 (pure streaming).
// K2 fused:  grid (4 H-chunks x 64 row-strips). Per block: inline LN of its
//   16 rows -> Ash/Xsh; GEMM1 (4 dbuf stages of 64 W1 rows) -> Hsh (relu);
//   GEMM2 (4 dbuf stages) -> atomicAdd(acc + 0.25*(xp+bf2)) into out.
//   Sum over the 4 chunk-blocks reconstructs out exactly (no init pass).

typedef short bf8_t __attribute__((ext_vector_type(8)));  // 8 bf16 = 4 VGPRs
typedef float f4_t  __attribute__((ext_vector_type(4)));

__device__ inline unsigned short f2bf(float f) {  // round-to-nearest-even
  unsigned u = __float_as_uint(f);
  u += 0x7fffu + ((u >> 16) & 1u);
  return (unsigned short)(u >> 16);
}

// 256 blocks x 256 thr x 8 floats = 524288 = |W1| + |W2|
__global__ __launch_bounds__(256) void prep_w(
    const float* __restrict__ W1, const float* __restrict__ W2,
    unsigned short* __restrict__ w1b, unsigned short* __restrict__ w2b) {
  const int gid = (blockIdx.x << 8) + threadIdx.x;
  const int e = gid << 3;
  const float* src; unsigned short* dst;
  if (e < 262144) { src = W1 + e;            dst = w1b + e; }
  else            { src = W2 + (e - 262144); dst = w2b + (e - 262144); }
  const float4 a = ((const float4*)src)[0];
  const float4 b = ((const float4*)src)[1];
  ushort4 oa, ob;
  oa.x = f2bf(a.x); oa.y = f2bf(a.y); oa.z = f2bf(a.z); oa.w = f2bf(a.w);
  ob.x = f2bf(b.x); ob.y = f2bf(b.y); ob.z = f2bf(b.z); ob.w = f2bf(b.w);
  ((ushort4*)dst)[0] = oa;
  ((ushort4*)dst)[1] = ob;
}

__global__ __launch_bounds__(256) void fused_kernel(
    const float* __restrict__ x,   const float* __restrict__ bp,
    const float* __restrict__ g2,  const float* __restrict__ b2,
    const float* __restrict__ bf1, const float* __restrict__ bf2,
    const unsigned short* __restrict__ w1b,   // [1024][256] bf16
    const unsigned short* __restrict__ w2b,   // [256][1024] bf16
    float* __restrict__ out) {                // [1024][256] fp32 (poisoned)
  __shared__ unsigned short Ash[16 * 264];    // h2 strip (A for GEMM1)
  __shared__ unsigned short Hsh[16 * 264];    // relu'd H (A for GEMM2)
  __shared__ float          Xsh[16 * 260];    // xp strip (fp32, for epilogue)
  __shared__ unsigned short Wsh[2][64 * 264]; // double-buffered weight stage
  const int tid = threadIdx.x;
  const int wave = tid >> 6, lane = tid & 63;
  const int quad = lane >> 4, l16 = lane & 15;
  const int bm = blockIdx.y << 4;             // strip base row (16 rows)
  const int c0 = blockIdx.x << 8;             // H-col chunk base (256 cols)

  // ---- inline LN: each lane owns 16 cols of one row; row fits in a wave ----
  {
    const int lr = (wave << 2) + (lane >> 4); // local row 0..15
    const int cb = l16 << 4;                  // col base
    const float* xr = x + ((bm + lr) << 8) + cb;
    float v[16];
    #pragma unroll
    for (int i = 0; i < 4; ++i) {
      const float4 t  = ((const float4*)xr)[i];
      const float4 pb = ((const float4*)(bp + cb))[i];
      v[4*i+0] = t.x + pb.x; v[4*i+1] = t.y + pb.y;
      v[4*i+2] = t.z + pb.z; v[4*i+3] = t.w + pb.w;
    }
    float s = 0.0f, s2 = 0.0f;
    #pragma unroll
    for (int i = 0; i < 16; ++i) { s += v[i]; s2 += v[i] * v[i]; }
    #pragma unroll
    for (int m = 1; m < 16; m <<= 1) {  // reduce across the row's 16 lanes
      s  += __shfl_xor(s, m);
      s2 += __shfl_xor(s2, m);
    }
    const float mu   = s * (1.0f / 256.0f);
    const float var  = s2 * (1.0f / 256.0f) - mu * mu;
    const float rstd = rsqrtf(var + 1e-5f);
    #pragma unroll
    for (int i = 0; i < 4; ++i) {
      const float4 gg = ((const float4*)(g2 + cb))[i];
      const float4 bb = ((const float4*)(b2 + cb))[i];
      ((float4*)&Xsh[lr * 260 + cb])[i] =
          make_float4(v[4*i+0], v[4*i+1], v[4*i+2], v[4*i+3]);
      ushort4 o;
      o.x = f2bf((v[4*i+0] - mu) * rstd * gg.x + bb.x);
      o.y = f2bf((v[4*i+1] - mu) * rstd * gg.y + bb.y);
      o.z = f2bf((v[4*i+2] - mu) * rstd * gg.z + bb.z);
      o.w = f2bf((v[4*i+3] - mu) * rstd * gg.w + bb.w);
      *(ushort4*)&Ash[lr * 264 + cb + (i << 2)] = o;
    }
  }

  // ---- double-buffered weight streaming ----
  uint4 pf[8];
  auto issueW1 = [&](int s) {
    #pragma unroll
    for (int j = 0; j < 8; ++j) {
      const int i = (j << 8) + tid, r = i >> 5, c = i & 31;
      pf[j] = *(const uint4*)&w1b[((c0 + (s << 6) + r) << 8) + (c << 3)];
    }
  };
  auto issueW2 = [&](int s) {
    #pragma unroll
    for (int j = 0; j < 8; ++j) {
      const int i = (j << 8) + tid, r = i >> 5, c = i & 31;
      pf[j] = *(const uint4*)&w2b[(((s << 6) + r) << 10) + c0 + (c << 3)];
    }
  };
  auto commit = [&](int p) {
    #pragma unroll
    for (int j = 0; j < 8; ++j) {
      const int i = (j << 8) + tid, r = i >> 5, c = i & 31;
      *(uint4*)&Wsh[p][r * 264 + (c << 3)] = pf[j];
    }
  };

  issueW1(0);
  commit(0);
  __syncthreads();  // Ash/Xsh + Wsh[0] visible

  // ---- GEMM1: Hsh = relu(Ash @ W1_chunk^T + bf1) ----
  for (int s = 0; s < 4; ++s) {
    if (s < 3) issueW1(s + 1); else issueW2(0);
    f4_t acc = {};
    #pragma unroll
    for (int ks = 0; ks < 8; ++ks) {
      const bf8_t a  = *(const bf8_t*)&Ash[l16 * 264 + (ks << 5) + (quad << 3)];
      const bf8_t bv = *(const bf8_t*)&Wsh[s & 1][((wave << 4) + l16) * 264 + (ks << 5) + (quad << 3)];
      acc = __builtin_amdgcn_mfma_f32_16x16x32_bf16(a, bv, acc, 0, 0, 0);
    }
    const int nl = (s << 6) + (wave << 4) + l16;
    const float bias = bf1[c0 + nl];
    #pragma unroll
    for (int r = 0; r < 4; ++r)
      Hsh[((quad << 2) + r) * 264 + nl] = f2bf(fmaxf(acc[r] + bias, 0.0f));
    commit((s + 1) & 1);
    __syncthreads();
  }

  // ---- GEMM2: out += Hsh @ W2[:,chunk]^T + 0.25*(xp + bf2) ----
  for (int s2 = 0; s2 < 4; ++s2) {
    if (s2 < 3) issueW2(s2 + 1);
    f4_t acc = {};
    #pragma unroll
    for (int ks = 0; ks < 8; ++ks) {
      const bf8_t a  = *(const bf8_t*)&Hsh[l16 * 264 + (ks << 5) + (quad << 3)];
      const bf8_t bv = *(const bf8_t*)&Wsh[s2 & 1][((wave << 4) + l16) * 264 + (ks << 5) + (quad << 3)];
      acc = __builtin_amdgcn_mfma_f32_16x16x32_bf16(a, bv, acc, 0, 0, 0);
    }
    const int n2 = (s2 << 6) + (wave << 4) + l16;
    const float bv2 = bf2[n2];
    #pragma unroll
    for (int r = 0; r < 4; ++r) {
      const int ml = (quad << 2) + r;
      const float base = 0.25f * (Xsh[ml * 260 + n2] + bv2);
      unsafeAtomicAdd(&out[((bm + ml) << 8) + n2], acc[r] + base);
    }
    if (s2 < 3) {
      commit((s2 + 1) & 1);
      __syncthreads();
    }
  }
}

extern "C" void kernel_launch(void* const* d_in, const int* in_sizes, int n_in,
                              void* d_out, int out_size, void* d_ws, size_t ws_size,
                              hipStream_t stream) {
  // inputs: x, Wt, Wp, bp, g1, b1, g2, b2, W1, bf1, W2, bf2
  const float* x   = (const float*)d_in[0];
  const float* bp  = (const float*)d_in[3];
  const float* g2  = (const float*)d_in[6];
  const float* b2  = (const float*)d_in[7];
  const float* W1  = (const float*)d_in[8];
  const float* bf1 = (const float*)d_in[9];
  const float* W2  = (const float*)d_in[10];
  const float* bf2 = (const float*)d_in[11];
  float* out = (float*)d_out;

  unsigned short* w1b = (unsigned short*)d_ws;   // 512 KB
  unsigned short* w2b = w1b + 262144;            // 512 KB

  prep_w<<<256, 256, 0, stream>>>(W1, W2, w1b, w2b);
  fused_kernel<<<dim3(4, 64), 256, 0, stream>>>(x, bp, g2, b2, bf1, bf2,
                                                w1b, w2b, out);
}

// Round 5
// 120.771 us; speedup vs baseline: 1.2548x; 1.2548x over previous
//
#include <hip/hip_runtime.h>

// B=2,T=512,C=256,HID=1024. ROWS=1024.
// Reference collapses (attn branch *0.0) to:
//   xp = x + bp;  out = xp + bf2 + relu(LN(xp,g2,b2) @ W1.T + bf1) @ W2.T
// K1 prep: rows [0,1024): h2 = bf16 LN, out_init = xp + bf2;
//          blocks [1024,1280): W1/W2 fp32 -> bf16 (8 floats/thread).
// K2 fused: grid (4 H-chunks x 64 strips). GEMM1(+bias,relu) -> Hsh ->
//           GEMM2 -> atomicAdd partials into pre-inited out.
// LDS row stride 272 ush (136 dw === 8 mod 32): 4 consecutive lanes' b128
// fragment reads cover all 32 banks (264 === 4 mod 32 aliased l16 & l16+8).

typedef short bf8_t __attribute__((ext_vector_type(8)));  // 8 bf16 = 4 VGPRs
typedef float f4_t  __attribute__((ext_vector_type(4)));

#define LSTR 272  // LDS row stride in ushorts

__device__ inline unsigned short f2bf(float f) {  // round-to-nearest-even
  unsigned u = __float_as_uint(f);
  u += 0x7fffu + ((u >> 16) & 1u);
  return (unsigned short)(u >> 16);
}

// blocks [0,1024): LN row + out init;  [1024,1280): weight fp32->bf16
__global__ __launch_bounds__(256) void prep_kernel(
    const float* __restrict__ x, const float* __restrict__ bp,
    const float* __restrict__ g2, const float* __restrict__ b2,
    const float* __restrict__ bf2,
    const float* __restrict__ W1, const float* __restrict__ W2,
    unsigned short* __restrict__ h2,
    unsigned short* __restrict__ w1b, unsigned short* __restrict__ w2b,
    float* __restrict__ out) {
  const int b = blockIdx.x, t = threadIdx.x;
  if (b < 1024) {
    const int idx = (b << 8) + t;
    const float v = x[idx] + bp[t];
    float s = v, s2 = v * v;
    #pragma unroll
    for (int off = 32; off > 0; off >>= 1) {
      s  += __shfl_down(s, off);
      s2 += __shfl_down(s2, off);
    }
    __shared__ float red[8];
    const int wave = t >> 6, lane = t & 63;
    if (lane == 0) { red[wave] = s; red[4 + wave] = s2; }
    __syncthreads();
    const float ts  = red[0] + red[1] + red[2] + red[3];
    const float ts2 = red[4] + red[5] + red[6] + red[7];
    const float mu   = ts * (1.0f / 256.0f);
    const float var  = ts2 * (1.0f / 256.0f) - mu * mu;
    const float rstd = rsqrtf(var + 1e-5f);
    h2[idx]  = f2bf((v - mu) * rstd * g2[t] + b2[t]);
    out[idx] = v + bf2[t];
  } else {
    const int gid = ((b - 1024) << 8) + t;
    const int e = gid << 3;
    const float* src; unsigned short* dst;
    if (e < 262144) { src = W1 + e;            dst = w1b + e; }
    else            { src = W2 + (e - 262144); dst = w2b + (e - 262144); }
    const float4 a = ((const float4*)src)[0];
    const float4 c = ((const float4*)src)[1];
    ushort4 oa, oc;
    oa.x = f2bf(a.x); oa.y = f2bf(a.y); oa.z = f2bf(a.z); oa.w = f2bf(a.w);
    oc.x = f2bf(c.x); oc.y = f2bf(c.y); oc.z = f2bf(c.z); oc.w = f2bf(c.w);
    ((ushort4*)dst)[0] = oa;
    ((ushort4*)dst)[1] = oc;
  }
}

// grid (4 chunks, 64 strips); block = 256 threads = 4 waves.
__global__ __launch_bounds__(256) void fused_ffn_kernel(
    const unsigned short* __restrict__ h2,   // [1024][256] bf16
    const unsigned short* __restrict__ w1b,  // [1024][256] bf16
    const unsigned short* __restrict__ w2b,  // [256][1024] bf16
    const float* __restrict__ bf1,           // [1024]
    float* __restrict__ out) {               // [1024][256] fp32, pre-inited
  __shared__ unsigned short Ash[16 * LSTR];  // h2 strip   (A for GEMM1)
  __shared__ unsigned short Hsh[16 * LSTR];  // relu'd H   (A for GEMM2)
  __shared__ unsigned short Wsh[64 * LSTR];  // streamed weight stage
  const int tid  = threadIdx.x;
  const int wave = tid >> 6, lane = tid & 63;
  const int quad = lane >> 4, l16 = lane & 15;
  const int bm = blockIdx.y << 4;            // strip base row (16 rows)
  const int c0 = blockIdx.x << 8;            // H-col chunk base (256 cols)

  // stage A strip: 16 rows x 256 bf16
  #pragma unroll
  for (int j = 0; j < 2; ++j) {
    const int i = (j << 8) + tid;            // 0..511 uint4 chunks
    const int r = i >> 5, c = i & 31;
    *(uint4*)&Ash[r * LSTR + (c << 3)] =
        *(const uint4*)&h2[((bm + r) << 8) + (c << 3)];
  }

  // ---- GEMM1: H[strip][chunk] = relu(A @ W1_chunk^T + bf1) -> Hsh ----
  for (int s = 0; s < 4; ++s) {
    __syncthreads();                         // Wsh free + (s=0) Ash visible
    #pragma unroll
    for (int j = 0; j < 8; ++j) {
      const int i = (j << 8) + tid;          // 0..2047 uint4 chunks
      const int r = i >> 5, c = i & 31;
      *(uint4*)&Wsh[r * LSTR + (c << 3)] =
          *(const uint4*)&w1b[((c0 + (s << 6) + r) << 8) + (c << 3)];
    }
    __syncthreads();
    f4_t acc = {};
    #pragma unroll
    for (int ks = 0; ks < 8; ++ks) {
      const bf8_t a  = *(const bf8_t*)&Ash[l16 * LSTR + (ks << 5) + (quad << 3)];
      const bf8_t bv = *(const bf8_t*)&Wsh[((wave << 4) + l16) * LSTR + (ks << 5) + (quad << 3)];
      acc = __builtin_amdgcn_mfma_f32_16x16x32_bf16(a, bv, acc, 0, 0, 0);
    }
    const int nl = (s << 6) + (wave << 4) + l16;   // H col within chunk
    const float bias = bf1[c0 + nl];
    #pragma unroll
    for (int r = 0; r < 4; ++r) {
      const float v = fmaxf(acc[r] + bias, 0.0f);
      Hsh[((quad << 2) + r) * LSTR + nl] = f2bf(v);  // C-layout -> A-layout
    }
  }

  // ---- GEMM2: out[strip][:] += Hsh @ W2[:, chunk]^T (K-partial) ----
  for (int s2 = 0; s2 < 4; ++s2) {
    __syncthreads();                         // Wsh free + Hsh complete
    #pragma unroll
    for (int j = 0; j < 8; ++j) {
      const int i = (j << 8) + tid;
      const int r = i >> 5, c = i & 31;
      *(uint4*)&Wsh[r * LSTR + (c << 3)] =
          *(const uint4*)&w2b[(((s2 << 6) + r) << 10) + c0 + (c << 3)];
    }
    __syncthreads();
    f4_t acc = {};
    #pragma unroll
    for (int ks = 0; ks < 8; ++ks) {
      const bf8_t a  = *(const bf8_t*)&Hsh[l16 * LSTR + (ks << 5) + (quad << 3)];
      const bf8_t bv = *(const bf8_t*)&Wsh[((wave << 4) + l16) * LSTR + (ks << 5) + (quad << 3)];
      acc = __builtin_amdgcn_mfma_f32_16x16x32_bf16(a, bv, acc, 0, 0, 0);
    }
    const int n2 = (s2 << 6) + (wave << 4) + l16;  // out col
    #pragma unroll
    for (int r = 0; r < 4; ++r) {
      const int m = bm + (quad << 2) + r;
      unsafeAtomicAdd(&out[(m << 8) + n2], acc[r]);
    }
  }
}

extern "C" void kernel_launch(void* const* d_in, const int* in_sizes, int n_in,
                              void* d_out, int out_size, void* d_ws, size_t ws_size,
                              hipStream_t stream) {
  // inputs: x, Wt, Wp, bp, g1, b1, g2, b2, W1, bf1, W2, bf2
  const float* x   = (const float*)d_in[0];
  const float* bp  = (const float*)d_in[3];
  const float* g2  = (const float*)d_in[6];
  const float* b2  = (const float*)d_in[7];
  const float* W1  = (const float*)d_in[8];
  const float* bf1 = (const float*)d_in[9];
  const float* W2  = (const float*)d_in[10];
  const float* bf2 = (const float*)d_in[11];
  float* out = (float*)d_out;

  unsigned short* h2  = (unsigned short*)d_ws;   // 512 KB
  unsigned short* w1b = h2 + 262144;             // 512 KB
  unsigned short* w2b = w1b + 262144;            // 512 KB

  prep_kernel<<<1280, 256, 0, stream>>>(x, bp, g2, b2, bf2, W1, W2,
                                        h2, w1b, w2b, out);
  fused_ffn_kernel<<<dim3(4, 64), 256, 0, stream>>>(h2, w1b, w2b, bf1, out);
}